// Round 9
// baseline (202.649 us; speedup 1.0000x reference)
//
#include <hip/hip_runtime.h>

#define NDIM 64
#define KNBR 16
#define NT 18            // curr + dest + 16 neighbors
#define HTS 1024         // hash table size (pow2); expected load ~324/1024
#define CAP_B1 128       // per-slot layer-1 edge bucket
#define CAP_B2 128       // per-target layer-2 edge bucket
#define EPT 16           // edges per scan thread (4 int4 loads in flight)
#define SCAN_TPB 256

// ---- workspace layout: [0, MEMSET_BYTES) zeroed by ONE small host memset ----
#define OFF_HT    0                                   // HTS ints: 0=empty, else v+1
#define OFF_BC2   (HTS*4)                             // 18 counters spaced 16 ints (1/line)
#define OFF_DONE  (OFF_BC2 + 32*16*4)                 // 1 int (done counter)
#define OFF_BC1   (OFF_DONE + 64)                     // HTS counters spaced 16 ints (1/line)
#define MEMSET_BYTES (OFF_BC1 + HTS*16*4)             // ~72.8 KB
// ---- below: written before read, no init ----
#define OFF_B1    (MEMSET_BYTES)                      // HTS*CAP_B1 ints (edge ids)
#define OFF_B2    (OFF_B1 + HTS*CAP_B1*4)             // 32*CAP_B2 ints (edge ids)
#define OFF_H     (OFF_B2 + 32*CAP_B2*4)              // HTS*64 floats (layer-1 h)

__device__ __forceinline__ int imin(int a, int b) { return a < b ? a : b; }

__device__ __forceinline__ unsigned hslot(int v) {
    return ((unsigned)v * 2654435761u) >> 22;         // top 10 bits
}

// Claim v into the hash table; returns its slot. CAS on scattered lines ->
// no serialized counter. Stale plain reads are resolved by the CAS result.
__device__ __forceinline__ int claim(int* ht, int v) {
    unsigned h = hslot(v);
    int cur = ht[h];
    while (true) {
        if (cur == v + 1) return (int)h;
        if (cur == 0) {
            int old = atomicCAS(&ht[h], 0, v + 1);
            if (old == 0) return (int)h;
            cur = old;
            continue;
        }
        h = (h + 1) & (HTS - 1);
        cur = ht[h];
    }
}

// Read-only lookup (table frozen after k_scan1): slot or -1.
__device__ __forceinline__ int lookup(const int* __restrict__ ht, int v) {
    unsigned h = hslot(v);
    while (true) {
        int cur = ht[h];
        if (cur == v + 1) return (int)h;
        if (cur == 0) return -1;
        h = (h + 1) & (HTS - 1);
    }
}

// Scan 1: one pass over dst. Claims the 18 targets (block 0); edges whose dst
// is a target -> per-target bucket2 (1 counter/line); sources claimed into ht.
__global__ void __launch_bounds__(SCAN_TPB)
k_scan1(const int* __restrict__ src, const int* __restrict__ dst, int E,
        const int* __restrict__ curr, const int* __restrict__ dest,
        const int* __restrict__ nbr,
        int* ht, int* bc2, int* b2) {
    int t0[NT];
    t0[0] = curr[0];
    t0[1] = dest[0];
    #pragma unroll
    for (int j = 0; j < KNBR; ++j) t0[2 + j] = nbr[j];
    if (blockIdx.x == 0 && threadIdx.x < NT)
        claim(ht, t0[threadIdx.x]);

    const int i4base = blockIdx.x * (SCAN_TPB * EPT / 4);
    const int nI4 = E >> 2;
    int dv[EPT];
    #pragma unroll
    for (int q = 0; q < EPT / 4; ++q) {
        int idx = i4base + q * SCAN_TPB + threadIdx.x;
        if (idx < nI4) {
            int4 v = ((const int4*)dst)[idx];
            dv[q*4+0] = v.x; dv[q*4+1] = v.y; dv[q*4+2] = v.z; dv[q*4+3] = v.w;
        } else {
            #pragma unroll
            for (int j = 0; j < 4; ++j) {
                int e = idx * 4 + j;
                dv[q*4+j] = (e < E) ? dst[e] : -1;
            }
        }
    }
    #pragma unroll
    for (int q = 0; q < EPT; ++q) {
        int dd = dv[q];
        if (dd < 0) continue;
        int e = (i4base + (q >> 2) * SCAN_TPB + threadIdx.x) * 4 + (q & 3);
        bool any = false;
        #pragma unroll
        for (int k = 0; k < NT; ++k) {
            if (dd == t0[k]) {
                any = true;
                int idx = atomicAdd(&bc2[k * 16], 1);
                if (idx < CAP_B2) b2[k * CAP_B2 + idx] = e;
            }
        }
        if (any) claim(ht, src[e]);
    }
}

// Scan 2: one pass over dst; membership via L1-resident 4 KB hash table;
// hits bucketed per slot (1 counter per line, scattered).
__global__ void __launch_bounds__(SCAN_TPB)
k_scan2(const int* __restrict__ dst, int E, const int* __restrict__ ht,
        int* bc1, int* b1) {
    const int i4base = blockIdx.x * (SCAN_TPB * EPT / 4);
    const int nI4 = E >> 2;
    int dv[EPT];
    #pragma unroll
    for (int q = 0; q < EPT / 4; ++q) {
        int idx = i4base + q * SCAN_TPB + threadIdx.x;
        if (idx < nI4) {
            int4 v = ((const int4*)dst)[idx];
            dv[q*4+0] = v.x; dv[q*4+1] = v.y; dv[q*4+2] = v.z; dv[q*4+3] = v.w;
        } else {
            #pragma unroll
            for (int j = 0; j < 4; ++j) {
                int e = idx * 4 + j;
                dv[q*4+j] = (e < E) ? dst[e] : -1;
            }
        }
    }
    #pragma unroll
    for (int q = 0; q < EPT; ++q) {
        int dd = dv[q];
        if (dd < 0) continue;
        int s = lookup(ht, dd);
        if (s >= 0) {
            int e = (i4base + (q >> 2) * SCAN_TPB + threadIdx.x) * 4 + (q & 3);
            int idx = atomicAdd(&bc1[s * 16], 1);
            if (idx < CAP_B1) b1[s * CAP_B1 + idx] = e;
        }
    }
}

// Fused layer-1 (all blocks, one hash slot per wave) + epilogue (the single
// last-finishing block: layer-2 MLPs at 18 targets + Q head, weights in LDS).
__global__ void __launch_bounds__(256)
k_node(const float* __restrict__ x, const int* __restrict__ src,
       const float* __restrict__ eattr,
       const int* __restrict__ curr, const int* __restrict__ dest,
       const int* __restrict__ nbr, const int* __restrict__ ht,
       const int* __restrict__ bc1, const int* __restrict__ b1,
       const int* __restrict__ bc2, const int* __restrict__ b2,
       const float* __restrict__ We1, const float* __restrict__ be1,
       const float* __restrict__ W1a, const float* __restrict__ b1a,
       const float* __restrict__ W1b, const float* __restrict__ b1b,
       const float* __restrict__ We2, const float* __restrict__ be2,
       const float* __restrict__ W2a, const float* __restrict__ b2a,
       const float* __restrict__ W2b, const float* __restrict__ b2b,
       const float* __restrict__ Wl1, const float* __restrict__ bl1,
       const float* __restrict__ Wl2, const float* __restrict__ bl2,
       float* __restrict__ hbuf, int* done, float* __restrict__ out) {
    const int wid = threadIdx.x >> 6, lane = threadIdx.x & 63;

    __shared__ float wA[NDIM * NDIM];      // W1a / W2a / Wl1 chunk0
    __shared__ float wB[NDIM * NDIM];      // W1b / W2b / Wl1 chunk1
    __shared__ float wC[NDIM * NDIM];      // Wl1 chunk2
    __shared__ int   s_iv[4][CAP_B1];
    __shared__ float s_fv[4][CAP_B1];
    __shared__ float s_t[4][NDIM];
    __shared__ float s_u[4][NDIM];
    __shared__ float s_outh[NT][NDIM];
    __shared__ int   s_last;

    const int sbase = blockIdx.x * 4;
    const int v4a = ht[sbase + 0], v4b = ht[sbase + 1];
    const int v4c = ht[sbase + 2], v4d = ht[sbase + 3];
    const bool haswork = (v4a | v4b | v4c | v4d) != 0;

    if (haswork) {
        // stage W1a/W1b (32 KB) into LDS
        const float4* A = (const float4*)W1a;
        const float4* B = (const float4*)W1b;
        float4* a = (float4*)wA;
        float4* b = (float4*)wB;
        #pragma unroll
        for (int q = 0; q < 4; ++q) {
            int i = q * 256 + threadIdx.x;
            a[i] = A[i];
            b[i] = B[i];
        }
        __syncthreads();

        int vv = (wid == 0) ? v4a : (wid == 1) ? v4b : (wid == 2) ? v4c : v4d;
        if (vv != 0) {
            int s = sbase + wid;
            int v = vv - 1;
            int m = imin(bc1[s * 16], CAP_B1);
            for (int i = lane; i < m; i += 64) {
                int e = b1[s * CAP_B1 + i];
                s_iv[wid][i] = src[e];
                s_fv[wid][i] = eattr[e];
            }
            __builtin_amdgcn_wave_barrier();
            float w = We1[lane], b0 = be1[lane];
            float a0 = x[(size_t)v * NDIM + lane], a1 = 0.f, a2 = 0.f, a3 = 0.f;
            int i = 0;
            for (; i + 3 < m; i += 4) {
                a0 += fmaxf(x[(size_t)s_iv[wid][i+0] * NDIM + lane] + fmaf(s_fv[wid][i+0], w, b0), 0.f);
                a1 += fmaxf(x[(size_t)s_iv[wid][i+1] * NDIM + lane] + fmaf(s_fv[wid][i+1], w, b0), 0.f);
                a2 += fmaxf(x[(size_t)s_iv[wid][i+2] * NDIM + lane] + fmaf(s_fv[wid][i+2], w, b0), 0.f);
                a3 += fmaxf(x[(size_t)s_iv[wid][i+3] * NDIM + lane] + fmaf(s_fv[wid][i+3], w, b0), 0.f);
            }
            for (; i < m; ++i)
                a0 += fmaxf(x[(size_t)s_iv[wid][i] * NDIM + lane] + fmaf(s_fv[wid][i], w, b0), 0.f);
            s_t[wid][lane] = (a0 + a1) + (a2 + a3);
            __builtin_amdgcn_wave_barrier();
            float m1 = b1a[lane];
            #pragma unroll 8
            for (int k = 0; k < NDIM; ++k) m1 = fmaf(s_t[wid][k], wA[k * NDIM + lane], m1);
            s_u[wid][lane] = fmaxf(m1, 0.f);
            __builtin_amdgcn_wave_barrier();
            float m2 = b1b[lane];
            #pragma unroll 8
            for (int k = 0; k < NDIM; ++k) m2 = fmaf(s_u[wid][k], wB[k * NDIM + lane], m2);
            hbuf[(size_t)s * NDIM + lane] = fmaxf(m2, 0.f);
        }
    }

    // ---- completion: single counter (256 arrivals ~ few us), unique last ----
    __syncthreads();
    if (threadIdx.x == 0) {
        __threadfence();   // release hbuf device-wide
        int idx = __hip_atomic_fetch_add(done, 1, __ATOMIC_ACQ_REL,
                                         __HIP_MEMORY_SCOPE_AGENT);
        s_last = (idx == gridDim.x - 1);
    }
    __syncthreads();
    if (!s_last) return;
    __threadfence();       // acquire all hbuf writes

    // ---- epilogue (one block): stage W2a/W2b, layer-2 MLPs at 18 targets ----
    {
        const float4* A = (const float4*)W2a;
        const float4* B = (const float4*)W2b;
        float4* a = (float4*)wA;
        float4* b = (float4*)wB;
        #pragma unroll
        for (int q = 0; q < 4; ++q) {
            int i = q * 256 + threadIdx.x;
            a[i] = A[i];
            b[i] = B[i];
        }
    }
    int t0[NT];
    t0[0] = curr[0];
    t0[1] = dest[0];
    #pragma unroll
    for (int j = 0; j < KNBR; ++j) t0[2 + j] = nbr[j];
    __syncthreads();

    for (int kt = wid; kt < NT; kt += 4) {
        int m = imin(bc2[kt * 16], CAP_B2);
        for (int i = lane; i < m; i += 64) {
            int e = b2[kt * CAP_B2 + i];
            s_iv[wid][i] = lookup(ht, src[e]);
            s_fv[wid][i] = eattr[e];
        }
        __builtin_amdgcn_wave_barrier();
        int sv = lookup(ht, t0[kt]);
        float w2e = We2[lane], b2e = be2[lane];
        float a0 = hbuf[(size_t)sv * NDIM + lane], a1 = 0.f, a2 = 0.f, a3 = 0.f;
        int i = 0;
        for (; i + 3 < m; i += 4) {
            int s0 = s_iv[wid][i+0], s1 = s_iv[wid][i+1], s2 = s_iv[wid][i+2], s3 = s_iv[wid][i+3];
            if (s0 >= 0) a0 += fmaxf(hbuf[(size_t)s0 * NDIM + lane] + fmaf(s_fv[wid][i+0], w2e, b2e), 0.f);
            if (s1 >= 0) a1 += fmaxf(hbuf[(size_t)s1 * NDIM + lane] + fmaf(s_fv[wid][i+1], w2e, b2e), 0.f);
            if (s2 >= 0) a2 += fmaxf(hbuf[(size_t)s2 * NDIM + lane] + fmaf(s_fv[wid][i+2], w2e, b2e), 0.f);
            if (s3 >= 0) a3 += fmaxf(hbuf[(size_t)s3 * NDIM + lane] + fmaf(s_fv[wid][i+3], w2e, b2e), 0.f);
        }
        for (; i < m; ++i) {
            int s = s_iv[wid][i];
            if (s >= 0) a0 += fmaxf(hbuf[(size_t)s * NDIM + lane] + fmaf(s_fv[wid][i], w2e, b2e), 0.f);
        }
        s_t[wid][lane] = (a0 + a1) + (a2 + a3);
        __builtin_amdgcn_wave_barrier();
        float m1 = b2a[lane];
        #pragma unroll 8
        for (int kk = 0; kk < NDIM; ++kk) m1 = fmaf(s_t[wid][kk], wA[kk * NDIM + lane], m1);
        s_u[wid][lane] = fmaxf(m1, 0.f);
        __builtin_amdgcn_wave_barrier();
        float m2 = b2b[lane];
        #pragma unroll 8
        for (int kk = 0; kk < NDIM; ++kk) m2 = fmaf(s_u[wid][kk], wB[kk * NDIM + lane], m2);
        s_outh[kt][lane] = m2;
    }
    __syncthreads();

    // ---- stage Wl1 (48 KB) into LDS, then Q head ----
    {
        const float4* W = (const float4*)Wl1;   // 3072 float4
        float4* a = (float4*)wA;
        float4* b = (float4*)wB;
        float4* c = (float4*)wC;
        #pragma unroll
        for (int q = 0; q < 4; ++q) {
            int i = q * 256 + threadIdx.x;
            a[i] = W[i];
            b[i] = W[i + 1024];
            c[i] = W[i + 2048];
        }
    }
    __syncthreads();

    for (int j = wid; j < KNBR; j += 4) {
        float acc = bl1[lane];
        #pragma unroll 8
        for (int i = 0; i < NDIM; ++i) acc = fmaf(s_outh[0][i], wA[i * NDIM + lane], acc);
        #pragma unroll 8
        for (int i = 0; i < NDIM; ++i) acc = fmaf(s_outh[1][i], wB[i * NDIM + lane], acc);
        #pragma unroll 8
        for (int i = 0; i < NDIM; ++i) acc = fmaf(s_outh[2 + j][i], wC[i * NDIM + lane], acc);
        acc = fmaxf(acc, 0.f) * Wl2[lane];
        #pragma unroll
        for (int off = 32; off > 0; off >>= 1) acc += __shfl_down(acc, off);
        if (lane == 0) out[j] = acc + bl2[0];
    }
}

extern "C" void kernel_launch(void* const* d_in, const int* in_sizes, int n_in,
                              void* d_out, int out_size, void* d_ws, size_t ws_size,
                              hipStream_t stream) {
    const float* x     = (const float*)d_in[0];
    const int*   eidx  = (const int*)d_in[1];
    const int    E     = in_sizes[1] / 2;
    const int*   src   = eidx;
    const int*   dstA  = eidx + E;
    const int*   curr  = (const int*)d_in[2];
    const int*   dest  = (const int*)d_in[3];
    const int*   nbr   = (const int*)d_in[4];
    const float* eattr = (const float*)d_in[5];
    const float* We1 = (const float*)d_in[6];
    const float* be1 = (const float*)d_in[7];
    const float* W1a = (const float*)d_in[8];
    const float* b1a = (const float*)d_in[9];
    const float* W1b = (const float*)d_in[10];
    const float* b1b = (const float*)d_in[11];
    const float* We2 = (const float*)d_in[12];
    const float* be2 = (const float*)d_in[13];
    const float* W2a = (const float*)d_in[14];
    const float* b2a = (const float*)d_in[15];
    const float* W2b = (const float*)d_in[16];
    const float* b2b = (const float*)d_in[17];
    const float* Wl1 = (const float*)d_in[18];
    const float* bl1 = (const float*)d_in[19];
    const float* Wl2 = (const float*)d_in[20];
    const float* bl2 = (const float*)d_in[21];

    char* ws = (char*)d_ws;
    int*   ht   = (int*)(ws + OFF_HT);
    int*   bc2  = (int*)(ws + OFF_BC2);
    int*   done = (int*)(ws + OFF_DONE);
    int*   bc1  = (int*)(ws + OFF_BC1);
    int*   b1   = (int*)(ws + OFF_B1);
    int*   b2   = (int*)(ws + OFF_B2);
    float* hbuf = (float*)(ws + OFF_H);

    // One small memset: hash table + spread counters + done (~73 KB).
    hipMemsetAsync(ws, 0, MEMSET_BYTES, stream);

    int scanBlocks = (E + SCAN_TPB * EPT - 1) / (SCAN_TPB * EPT);   // 196
    k_scan1<<<scanBlocks, SCAN_TPB, 0, stream>>>(src, dstA, E, curr, dest, nbr,
                                                 ht, bc2, b2);
    k_scan2<<<scanBlocks, SCAN_TPB, 0, stream>>>(dstA, E, ht, bc1, b1);
    k_node<<<HTS / 4, 256, 0, stream>>>(x, src, eattr, curr, dest, nbr, ht,
                                        bc1, b1, bc2, b2,
                                        We1, be1, W1a, b1a, W1b, b1b,
                                        We2, be2, W2a, b2a, W2b, b2b,
                                        Wl1, bl1, Wl2, bl2,
                                        hbuf, done, (float*)d_out);
}